// Round 1
// baseline (144.462 us; speedup 1.0000x reference)
//
#include <hip/hip_runtime.h>

#define NB 64
#define NH 16
#define HD 256
#define NF 4096

typedef float f4 __attribute__((ext_vector_type(4)));

__launch_bounds__(256, 4)
__global__ void mlstm_kernel(const float* __restrict__ q, const float* __restrict__ k,
                             const float* __restrict__ v, const float* __restrict__ c,
                             const float* __restrict__ n, const float* __restrict__ m,
                             const float* __restrict__ wi, const float* __restrict__ wib,
                             const float* __restrict__ wf, const float* __restrict__ wfb,
                             const float* __restrict__ lns,
                             float* __restrict__ out_c, float* __restrict__ out_n,
                             float* __restrict__ out_m, float* __restrict__ out_h) {
    // XCD-aware swizzle: 1024 blocks, 8 XCDs -> each XCD gets a contiguous
    // chunk of 128 logical workgroups (= 8 batches), so qkv + gate weights
    // re-reads across the 16 heads of a batch hit the local L2.
    const int bid = blockIdx.x;
    const int wg  = (bid & 7) * (NB * NH / 8) + (bid >> 3);
    const int b = wg >> 4;
    const int h = wg & 15;
    const int t = threadIdx.x;

    __shared__ __align__(16) float qh_s[HD];
    __shared__ __align__(16) float kh_s[HD];
    __shared__ __align__(16) float vh_s[HD];
    __shared__ __align__(16) float n_s[HD];
    __shared__ float redA[256];
    __shared__ float redB[256];
    __shared__ f4 nomp[256];
    __shared__ float sc[4];   // i_prime, f_prime, m_new, denom_eff

    // ---- stage head vectors ----
    const int hoff = b * NF + h * HD;
    qh_s[t] = q[hoff + t];
    kh_s[t] = k[hoff + t] * 0.0625f;   // 1/sqrt(256)
    vh_s[t] = v[hoff + t];
    n_s[t]  = n[(b * NH + h) * HD + t];

    // ---- gate dot products over qkv (3F = 12288) ----
    float si = 0.f, sf = 0.f;
    for (int r = t; r < 3 * NF; r += 256) {
        float x;
        if (r < NF)          x = q[b * NF + r];
        else if (r < 2 * NF) x = k[b * NF + r - NF];
        else                 x = v[b * NF + r - 2 * NF];
        si = fmaf(x, wi[r * NH + h], si);
        sf = fmaf(x, wf[r * NH + h], sf);
    }
    redA[t] = si;
    redB[t] = sf;
    __syncthreads();
    for (int s = 128; s > 0; s >>= 1) {
        if (t < s) { redA[t] += redA[t + s]; redB[t] += redB[t + s]; }
        __syncthreads();
    }
    if (t == 0) {
        const float it_ = redA[0] + wib[h];
        const float ft_ = redB[0] + wfb[h];
        // log_f = -softplus(-ft) = -(max(-ft,0) + log1p(exp(-|ft|)))
        const float lf = -(fmaxf(-ft_, 0.f) + log1pf(expf(-fabsf(ft_))));
        const float mo = m[b * NH + h];
        const float mn = fmaxf(lf + mo, it_);
        const float ip = expf(it_ - mn);
        const float fp = expf(lf + mo - mn);
        out_m[b * NH + h] = mn;
        sc[0] = ip; sc[1] = fp; sc[2] = mn;
    }
    __syncthreads();
    const float ip = sc[0], fp = sc[1], mn = sc[2];

    // ---- n_new and denominator dot ----
    const float nn = fp * n_s[t] + ip * kh_s[t];
    out_n[(b * NH + h) * HD + t] = nn;
    redA[t] = qh_s[t] * nn;
    __syncthreads();
    for (int s = 128; s > 0; s >>= 1) {
        if (t < s) redA[t] += redA[t + s];
        __syncthreads();
    }
    if (t == 0) sc[3] = fmaxf(fabsf(redA[0]), expf(-mn)) + 1e-6f;
    // (barrier before sc[3] is read comes from the nomp sync below)

    // ---- streaming c update: 4 waves x 64 lanes, 4 cols (float4) per lane ----
    const int rg = t >> 6;           // row group 0..3
    const int ci = t & 63;           // column-quad index
    const int j0 = ci * 4;
    const long base = (long)(b * NH + h) * HD * HD;

    f4 vj = *(const f4*)&vh_s[j0];
    vj *= ip;
    f4 nom = {0.f, 0.f, 0.f, 0.f};

    const float* cin  = c     + base + (long)rg * 64 * HD + j0;
    float*       cout = out_c + base + (long)rg * 64 * HD + j0;
    #pragma unroll 4
    for (int ii = 0; ii < 64; ++ii) {
        const int i = rg * 64 + ii;
        const f4 cv = __builtin_nontemporal_load((const f4*)(cin + (long)ii * HD));
        const f4 cn = fp * cv + kh_s[i] * vj;
        __builtin_nontemporal_store(cn, (f4*)(cout + (long)ii * HD));
        nom += qh_s[i] * cn;
    }
    nomp[t] = nom;
    __syncthreads();

    // ---- nominator reduce, h_tilde, LayerNorm (wave 0 only) ----
    if (t < 64) {
        const f4 nm = nomp[t] + nomp[t + 64] + nomp[t + 128] + nomp[t + 192];
        const float dn = sc[3];
        const f4 ht = nm / dn;
        float s1 = ht.x + ht.y + ht.z + ht.w;
        float s2 = ht.x * ht.x + ht.y * ht.y + ht.z * ht.z + ht.w * ht.w;
        #pragma unroll
        for (int o = 32; o > 0; o >>= 1) {
            s1 += __shfl_xor(s1, o);
            s2 += __shfl_xor(s2, o);
        }
        const float mu  = s1 * (1.f / 256.f);
        const float var = s2 * (1.f / 256.f) - mu * mu;
        const float inv = rsqrtf(var + 1e-6f);
        const f4 ls = *(const f4*)&lns[h * HD + j0];
        const f4 o4 = (ht - mu) * inv * ls;
        *(f4*)&out_h[b * NF + h * HD + j0] = o4;
    }
}

extern "C" void kernel_launch(void* const* d_in, const int* in_sizes, int n_in,
                              void* d_out, int out_size, void* d_ws, size_t ws_size,
                              hipStream_t stream) {
    const float* q   = (const float*)d_in[0];
    const float* k   = (const float*)d_in[1];
    const float* v   = (const float*)d_in[2];
    const float* c   = (const float*)d_in[3];
    const float* n   = (const float*)d_in[4];
    const float* m   = (const float*)d_in[5];
    const float* wi  = (const float*)d_in[6];
    const float* wib = (const float*)d_in[7];
    const float* wf  = (const float*)d_in[8];
    const float* wfb = (const float*)d_in[9];
    const float* lns = (const float*)d_in[10];

    float* out   = (float*)d_out;
    float* out_c = out;                                   // B*H*HD*HD
    float* out_n = out_c + (size_t)NB * NH * HD * HD;     // B*H*HD
    float* out_m = out_n + (size_t)NB * NH * HD;          // B*H
    float* out_h = out_m + (size_t)NB * NH;               // B*F

    mlstm_kernel<<<NB * NH, 256, 0, stream>>>(q, k, v, c, n, m, wi, wib, wf, wfb,
                                              lns, out_c, out_n, out_m, out_h);
}

// Round 2
// 140.228 us; speedup vs baseline: 1.0302x; 1.0302x over previous
//
#include <hip/hip_runtime.h>

#define NB 64
#define NH 16
#define HD 256
#define NF 4096

typedef float f4 __attribute__((ext_vector_type(4)));

// ---------------------------------------------------------------- K1: gates
// One block per batch. Each thread walks r = t, t+1024, ... over 3F=12288 and
// reads the 16-head weight rows CONTIGUOUSLY (64B per lane, coalesced), fixing
// the stride-64B over-fetch of the fused version. Wave shuffle-reduce, then
// cross-wave LDS reduce, then 16 threads compute the per-head gate scalars.
__launch_bounds__(1024, 1)
__global__ void gates_kernel(const float* __restrict__ q, const float* __restrict__ k,
                             const float* __restrict__ v, const float* __restrict__ m,
                             const float* __restrict__ wi, const float* __restrict__ wib,
                             const float* __restrict__ wf, const float* __restrict__ wfb,
                             float* __restrict__ out_m, float* __restrict__ ws_sc) {
    const int b = blockIdx.x;
    const int t = threadIdx.x;

    float si[16], sf[16];
    #pragma unroll
    for (int h = 0; h < 16; ++h) { si[h] = 0.f; sf[h] = 0.f; }

    for (int r = t; r < 3 * NF; r += 1024) {
        float x;
        if (r < NF)          x = q[b * NF + r];
        else if (r < 2 * NF) x = k[b * NF + r - NF];
        else                 x = v[b * NF + r - 2 * NF];
        const f4* wr = (const f4*)(wi + (size_t)r * 16);
        const f4* fr = (const f4*)(wf + (size_t)r * 16);
        #pragma unroll
        for (int g = 0; g < 4; ++g) {
            const f4 a = wr[g];
            const f4 c_ = fr[g];
            si[4*g+0] = fmaf(x, a.x, si[4*g+0]);
            si[4*g+1] = fmaf(x, a.y, si[4*g+1]);
            si[4*g+2] = fmaf(x, a.z, si[4*g+2]);
            si[4*g+3] = fmaf(x, a.w, si[4*g+3]);
            sf[4*g+0] = fmaf(x, c_.x, sf[4*g+0]);
            sf[4*g+1] = fmaf(x, c_.y, sf[4*g+1]);
            sf[4*g+2] = fmaf(x, c_.z, sf[4*g+2]);
            sf[4*g+3] = fmaf(x, c_.w, sf[4*g+3]);
        }
    }
    // wave reduce all 32 accumulators
    #pragma unroll
    for (int h = 0; h < 16; ++h) {
        #pragma unroll
        for (int o = 32; o > 0; o >>= 1) {
            si[h] += __shfl_xor(si[h], o);
            sf[h] += __shfl_xor(sf[h], o);
        }
    }
    __shared__ float lds[16][32];
    const int wv = t >> 6;
    if ((t & 63) == 0) {
        #pragma unroll
        for (int h = 0; h < 16; ++h) { lds[wv][h] = si[h]; lds[wv][16 + h] = sf[h]; }
    }
    __syncthreads();
    if (t < 32) {
        float s = 0.f;
        #pragma unroll
        for (int w = 0; w < 16; ++w) s += lds[w][t];
        lds[0][t] = s;  // column-private: safe
    }
    __syncthreads();
    if (t < 16) {
        const float it_ = lds[0][t] + wib[t];
        const float ft_ = lds[0][16 + t] + wfb[t];
        const float lf  = -(fmaxf(-ft_, 0.f) + log1pf(expf(-fabsf(ft_))));
        const float mo  = m[b * 16 + t];
        const float mn  = fmaxf(lf + mo, it_);
        out_m[b * 16 + t] = mn;
        ws_sc[(b * 16 + t) * 2 + 0] = expf(it_ - mn);       // i_prime
        ws_sc[(b * 16 + t) * 2 + 1] = expf(lf + mo - mn);   // f_prime
    }
}

// ---------------------------------------------------------------- K2: stream c
// One block per (b,h,quarter): 4 waves x 16 rows, lane owns 4 consecutive
// columns (f4). Plain loads for c (L3-cacheable, 268MB nearly fits in 256MB
// L3), nontemporal stores for c_new (don't evict c). Explicit 8-deep load
// batches for MLP. Partial column-nominator to ws.
__launch_bounds__(256, 8)
__global__ void stream_kernel(const float* __restrict__ q, const float* __restrict__ k,
                              const float* __restrict__ v, const float* __restrict__ c,
                              const float* __restrict__ ws_sc,
                              float* __restrict__ out_c, float* __restrict__ ws_part) {
    const int bid = blockIdx.x;
    const int sw  = (bid & 7) * 512 + (bid >> 3);   // XCD swizzle (4096 % 8 == 0)
    const int bh  = sw >> 2;
    const int qt  = sw & 3;
    const int b = bh >> 4, h = bh & 15;
    const int t = threadIdx.x;

    __shared__ __align__(16) f4 vip_s[64];
    __shared__ float kh_s[64], qh_s[64];
    __shared__ f4 nomp[256];

    const float ip = ws_sc[bh * 2 + 0];
    const float fp = ws_sc[bh * 2 + 1];
    const int hoff = b * NF + h * HD;
    const int i0   = qt * 64;

    if (t < 64) {
        kh_s[t] = k[hoff + i0 + t] * 0.0625f;   // 1/sqrt(256)
        qh_s[t] = q[hoff + i0 + t];
    } else if (t < 128) {
        const int j = t - 64;
        const f4 vv = *(const f4*)(v + hoff + j * 4);
        vip_s[j] = vv * ip;
    }
    __syncthreads();

    const int w    = t >> 6;       // wave 0..3 -> 16 rows each
    const int lane = t & 63;
    const int j0   = lane * 4;
    const f4 vip   = vip_s[lane];
    const int r0   = i0 + w * 16;
    const long base = (long)bh * HD * HD;
    const float* cin  = c     + base + (long)r0 * HD + j0;
    float*       cout = out_c + base + (long)r0 * HD + j0;

    f4 nom = {0.f, 0.f, 0.f, 0.f};
    #pragma unroll
    for (int bb = 0; bb < 2; ++bb) {
        f4 cb[8];
        #pragma unroll
        for (int u = 0; u < 8; ++u)
            cb[u] = *(const f4*)(cin + (long)(bb * 8 + u) * HD);
        #pragma unroll
        for (int u = 0; u < 8; ++u) {
            const int rr = bb * 8 + u;
            const f4 cn = fp * cb[u] + kh_s[w * 16 + rr] * vip;
            __builtin_nontemporal_store(cn, (f4*)(cout + (long)rr * HD));
            nom += qh_s[w * 16 + rr] * cn;
        }
    }
    nomp[t] = nom;
    __syncthreads();
    if (t < 64) {
        const f4 s = nomp[t] + nomp[t + 64] + nomp[t + 128] + nomp[t + 192];
        *(f4*)(ws_part + ((long)bh * 4 + qt) * HD + j0) = s;
    }
}

// ---------------------------------------------------------------- K3: finalize
// One block per (b,h): n_new + denominator + nominator gather + LayerNorm.
__launch_bounds__(256, 4)
__global__ void finalize_kernel(const float* __restrict__ q, const float* __restrict__ k,
                                const float* __restrict__ n, const float* __restrict__ ws_sc,
                                const float* __restrict__ ws_part,
                                const float* __restrict__ out_m, const float* __restrict__ lns,
                                float* __restrict__ out_n, float* __restrict__ out_h) {
    const int bh = blockIdx.x;
    const int b = bh >> 4, h = bh & 15;
    const int t = threadIdx.x;

    const float ip = ws_sc[bh * 2 + 0];
    const float fp = ws_sc[bh * 2 + 1];
    const float mn = out_m[bh];
    const int hoff = b * NF + h * HD;

    const float kh = k[hoff + t] * 0.0625f;
    const float nn = fp * n[(long)bh * HD + t] + ip * kh;
    out_n[(long)bh * HD + t] = nn;

    __shared__ float redD[4], redA[4], redB[4];
    float d = q[hoff + t] * nn;
    #pragma unroll
    for (int o = 32; o > 0; o >>= 1) d += __shfl_xor(d, o);
    if ((t & 63) == 0) redD[t >> 6] = d;
    __syncthreads();
    const float denom = fmaxf(fabsf(redD[0] + redD[1] + redD[2] + redD[3]),
                              expf(-mn)) + 1e-6f;

    const float nom = ws_part[((long)bh * 4 + 0) * HD + t]
                    + ws_part[((long)bh * 4 + 1) * HD + t]
                    + ws_part[((long)bh * 4 + 2) * HD + t]
                    + ws_part[((long)bh * 4 + 3) * HD + t];
    const float ht = nom / denom;

    float s1 = ht, s2 = ht * ht;
    #pragma unroll
    for (int o = 32; o > 0; o >>= 1) { s1 += __shfl_xor(s1, o); s2 += __shfl_xor(s2, o); }
    if ((t & 63) == 0) { redA[t >> 6] = s1; redB[t >> 6] = s2; }
    __syncthreads();
    s1 = redA[0] + redA[1] + redA[2] + redA[3];
    s2 = redB[0] + redB[1] + redB[2] + redB[3];
    const float mu  = s1 * (1.f / 256.f);
    const float var = s2 * (1.f / 256.f) - mu * mu;
    const float inv = rsqrtf(var + 1e-6f);
    out_h[b * NF + h * HD + t] = (ht - mu) * inv * lns[h * HD + t];
}

extern "C" void kernel_launch(void* const* d_in, const int* in_sizes, int n_in,
                              void* d_out, int out_size, void* d_ws, size_t ws_size,
                              hipStream_t stream) {
    const float* q   = (const float*)d_in[0];
    const float* k   = (const float*)d_in[1];
    const float* v   = (const float*)d_in[2];
    const float* c   = (const float*)d_in[3];
    const float* n   = (const float*)d_in[4];
    const float* m   = (const float*)d_in[5];
    const float* wi  = (const float*)d_in[6];
    const float* wib = (const float*)d_in[7];
    const float* wf  = (const float*)d_in[8];
    const float* wfb = (const float*)d_in[9];
    const float* lns = (const float*)d_in[10];

    float* out   = (float*)d_out;
    float* out_c = out;                                   // B*H*HD*HD
    float* out_n = out_c + (size_t)NB * NH * HD * HD;     // B*H*HD
    float* out_m = out_n + (size_t)NB * NH * HD;          // B*H
    float* out_h = out_m + (size_t)NB * NH;               // B*F

    float* ws_sc   = (float*)d_ws;                        // 1024 * 2 floats
    float* ws_part = ws_sc + 2048;                        // 1024 * 4 * 256 floats (4MB)

    gates_kernel<<<NB, 1024, 0, stream>>>(q, k, v, m, wi, wib, wf, wfb, out_m, ws_sc);
    stream_kernel<<<NB * NH * 4, 256, 0, stream>>>(q, k, v, c, ws_sc, out_c, ws_part);
    finalize_kernel<<<NB * NH, 256, 0, stream>>>(q, k, n, ws_sc, ws_part, out_m, lns,
                                                 out_n, out_h);
}